// Round 1
// baseline (339.835 us; speedup 1.0000x reference)
//
#include <hip/hip_runtime.h>
#include <hip/hip_bf16.h>
#include <stdint.h>

#define N_ROWS 262144
#define FEAT 1024
#define N_CORES 4096
#define HDIM 1024
#define BN_EPS 1e-5f

typedef __attribute__((ext_vector_type(8))) short bf16x8;
typedef __attribute__((ext_vector_type(4))) float f32x4;

__device__ __forceinline__ unsigned short f2bf(float f) {
  __hip_bfloat16 h = __float2bfloat16(f);
  return __builtin_bit_cast(unsigned short, h);
}
__device__ __forceinline__ float bf2f(unsigned short u) {
  unsigned int x = ((unsigned int)u) << 16;
  return __builtin_bit_cast(float, x);
}

// ---------------------------------------------------------------- seg-sum
// one block per segment; 256 threads x float4 covers 1024 features
__global__ __launch_bounds__(256)
void k_segsum(const float* __restrict__ x, const int* __restrict__ corelen,
              unsigned short* __restrict__ aggb) {
  const int seg = blockIdx.x;
  const int t = threadIdx.x;
  const int start = corelen[seg];
  const int end = (seg + 1 < N_CORES) ? corelen[seg + 1] : N_ROWS;
  float4 acc = make_float4(0.f, 0.f, 0.f, 0.f);
  const float* xp = x + (size_t)start * FEAT + t * 4;
  for (int r = start; r < end; ++r) {
    const float4 v = *(const float4*)xp;
    acc.x += v.x; acc.y += v.y; acc.z += v.z; acc.w += v.w;
    xp += FEAT;
  }
  ushort4 o;
  o.x = f2bf(acc.x); o.y = f2bf(acc.y); o.z = f2bf(acc.z); o.w = f2bf(acc.w);
  *(ushort4*)(aggb + (size_t)seg * FEAT + t * 4) = o;
}

// ------------------------------------------- W [K,N] f32 -> Wt [N,K] bf16
__global__ __launch_bounds__(256)
void k_transpose_bf16(const float* __restrict__ W, unsigned short* __restrict__ Wt) {
  __shared__ unsigned short tile[32][33];
  const int tx = threadIdx.x, ty = threadIdx.y;
  const int n0 = blockIdx.x * 32, k0 = blockIdx.y * 32;
#pragma unroll
  for (int i = 0; i < 4; ++i)
    tile[ty + 8 * i][tx] = f2bf(W[(size_t)(k0 + ty + 8 * i) * HDIM + n0 + tx]);
  __syncthreads();
#pragma unroll
  for (int i = 0; i < 4; ++i)
    Wt[(size_t)(n0 + ty + 8 * i) * HDIM + k0 + tx] = tile[tx][ty + 8 * i];
}

// ------------------------------------------------------------------ GEMM
// C[M,N] = A[M,K](bf16) * Bt[N,K](bf16)^T + bias ; 128x128 tile, 4 waves,
// each wave 64x64 = 4x4 fragments of mfma_f32_16x16x32_bf16
__global__ __launch_bounds__(256)
void k_gemm_bt(const unsigned short* __restrict__ A,
               const unsigned short* __restrict__ Bt,
               const float* __restrict__ bias,
               float* __restrict__ C,
               int M, int N, int K) {
  __shared__ unsigned short As[128][40];  // +8 pad: 80B row stride, 2-way bank alias (free)
  __shared__ unsigned short Bs[128][40];
  const int t = threadIdx.x;
  const int lane = t & 63;
  const int w = t >> 6;
  const int tileM = blockIdx.x * 128;
  const int tileN = blockIdx.y * 128;
  const int wr = (w >> 1) * 64;
  const int wc = (w & 1) * 64;
  const int srow = t >> 2;         // staging row 0..63
  const int scol = (t & 3) * 8;    // staging k-offset 0,8,16,24
  const int fr = lane & 15;        // fragment row/col within 16
  const int kk = (lane >> 4) * 8;  // fragment k-offset

  f32x4 acc[4][4] = {};

  const unsigned short* pA0 = A + (size_t)(tileM + srow) * K + scol;
  const unsigned short* pA1 = A + (size_t)(tileM + srow + 64) * K + scol;
  const unsigned short* pB0 = Bt + (size_t)(tileN + srow) * K + scol;
  const unsigned short* pB1 = Bt + (size_t)(tileN + srow + 64) * K + scol;

  for (int k0 = 0; k0 < K; k0 += 32) {
    const bf16x8 a0 = *(const bf16x8*)(pA0 + k0);
    const bf16x8 a1 = *(const bf16x8*)(pA1 + k0);
    const bf16x8 b0 = *(const bf16x8*)(pB0 + k0);
    const bf16x8 b1 = *(const bf16x8*)(pB1 + k0);
    __syncthreads();
    *(bf16x8*)(&As[srow][scol]) = a0;
    *(bf16x8*)(&As[srow + 64][scol]) = a1;
    *(bf16x8*)(&Bs[srow][scol]) = b0;
    *(bf16x8*)(&Bs[srow + 64][scol]) = b1;
    __syncthreads();
    bf16x8 af[4], bfr[4];
#pragma unroll
    for (int m = 0; m < 4; ++m) af[m] = *(const bf16x8*)(&As[wr + m * 16 + fr][kk]);
#pragma unroll
    for (int n = 0; n < 4; ++n) bfr[n] = *(const bf16x8*)(&Bs[wc + n * 16 + fr][kk]);
#pragma unroll
    for (int m = 0; m < 4; ++m)
#pragma unroll
      for (int n = 0; n < 4; ++n)
        acc[m][n] = __builtin_amdgcn_mfma_f32_16x16x32_bf16(af[m], bfr[n], acc[m][n], 0, 0, 0);
  }

  // C/D layout (HW-verified): col = lane&15, row = (lane>>4)*4 + reg
  const int cr = (lane >> 4) * 4;
  const int cc = lane & 15;
#pragma unroll
  for (int m = 0; m < 4; ++m)
#pragma unroll
    for (int n = 0; n < 4; ++n) {
      const int col = tileN + wc + n * 16 + cc;
      const float bv = bias[col];
      float* cp = C + (size_t)(tileM + wr + m * 16 + cr) * N + col;
#pragma unroll
      for (int j = 0; j < 4; ++j)
        cp[(size_t)j * N] = acc[m][n][j] + bv;
    }
}

// ------------------------------------------------- BN column stats (sum, sumsq)
__global__ __launch_bounds__(256)
void k_colstats(const float* __restrict__ Hp, float* __restrict__ sums,
                float* __restrict__ sumsq) {
  const int c = blockIdx.x * 256 + threadIdx.x;
  const int r0 = blockIdx.y * 128;
  float s = 0.f, s2 = 0.f;
  for (int r = r0; r < r0 + 128; ++r) {
    const float v = Hp[(size_t)r * HDIM + c];
    s += v; s2 += v * v;
  }
  atomicAdd(&sums[c], s);
  atomicAdd(&sumsq[c], s2);
}

__global__ __launch_bounds__(256)
void k_finalize(const float* __restrict__ sums, const float* __restrict__ sumsq,
                const float* __restrict__ g, const float* __restrict__ be,
                float* __restrict__ scale, float* __restrict__ shift) {
  const int c = blockIdx.x * 256 + threadIdx.x;
  const float mean = sums[c] * (1.f / N_CORES);
  const float var = sumsq[c] * (1.f / N_CORES) - mean * mean;
  const float sc = g[c] * rsqrtf(var + BN_EPS);
  scale[c] = sc;
  shift[c] = be[c] - mean * sc;
}

// ---------------------------------------- normalize + ReLU + cast to bf16
__global__ __launch_bounds__(256)
void k_norm_relu(const float* __restrict__ Hp, const float* __restrict__ scale,
                 const float* __restrict__ shift, unsigned short* __restrict__ Ab) {
  const size_t i4 = ((size_t)blockIdx.x * 256 + threadIdx.x) * 4;
  const float4 v = *(const float4*)(Hp + i4);
  const int c = (int)(i4 & (HDIM - 1));
  const float4 sc = *(const float4*)(scale + c);
  const float4 sh = *(const float4*)(shift + c);
  ushort4 o;
  o.x = f2bf(fmaxf(v.x * sc.x + sh.x, 0.f));
  o.y = f2bf(fmaxf(v.y * sc.y + sh.y, 0.f));
  o.z = f2bf(fmaxf(v.z * sc.z + sh.z, 0.f));
  o.w = f2bf(fmaxf(v.w * sc.w + sh.w, 0.f));
  *(ushort4*)(Ab + i4) = o;
}

// ----------------------------------------------- final layer [4096,1024]x[1024,2]
__global__ __launch_bounds__(256)
void k_final(const unsigned short* __restrict__ Ab, const float* __restrict__ W4,
             const float* __restrict__ b4, float* __restrict__ out) {
  const int t = threadIdx.x;
  const int w = t >> 6, lane = t & 63;
  const int row = blockIdx.x * 4 + w;
  const unsigned short* a = Ab + (size_t)row * HDIM + lane * 16;
  const bf16x8 v0 = *(const bf16x8*)a;
  const bf16x8 v1 = *(const bf16x8*)(a + 8);
  float s0 = 0.f, s1 = 0.f;
  const int kbase = lane * 16;
#pragma unroll
  for (int j = 0; j < 8; ++j) {
    const float av = bf2f((unsigned short)v0[j]);
    s0 += av * W4[(kbase + j) * 2 + 0];
    s1 += av * W4[(kbase + j) * 2 + 1];
  }
#pragma unroll
  for (int j = 0; j < 8; ++j) {
    const float av = bf2f((unsigned short)v1[j]);
    s0 += av * W4[(kbase + 8 + j) * 2 + 0];
    s1 += av * W4[(kbase + 8 + j) * 2 + 1];
  }
#pragma unroll
  for (int off = 32; off >= 1; off >>= 1) {
    s0 += __shfl_down(s0, off, 64);
    s1 += __shfl_down(s1, off, 64);
  }
  if (lane == 0) {
    out[row * 2 + 0] = s0 + b4[0];
    out[row * 2 + 1] = s1 + b4[1];
  }
}

extern "C" void kernel_launch(void* const* d_in, const int* in_sizes, int n_in,
                              void* d_out, int out_size, void* d_ws, size_t ws_size,
                              hipStream_t stream) {
  (void)in_sizes; (void)n_in; (void)out_size; (void)ws_size;
  const float* x       = (const float*)d_in[0];
  const int* corelen   = (const int*)d_in[1];
  const float* W1  = (const float*)d_in[2];
  const float* b1  = (const float*)d_in[3];
  const float* g1  = (const float*)d_in[4];
  const float* be1 = (const float*)d_in[5];
  const float* W2  = (const float*)d_in[6];
  const float* b2  = (const float*)d_in[7];
  const float* g2  = (const float*)d_in[8];
  const float* be2 = (const float*)d_in[9];
  const float* W3  = (const float*)d_in[10];
  const float* b3  = (const float*)d_in[11];
  const float* g3  = (const float*)d_in[12];
  const float* be3 = (const float*)d_in[13];
  const float* W4  = (const float*)d_in[14];
  const float* b4  = (const float*)d_in[15];
  float* out = (float*)d_out;

  char* ws = (char*)d_ws;
  float* Hpre          = (float*)(ws);                        // 16 MB: [4096,1024] f32
  unsigned short* Abf  = (unsigned short*)(ws + (16u << 20)); //  8 MB: [4096,1024] bf16
  unsigned short* Wt   = (unsigned short*)(ws + (24u << 20)); //  2 MB: [1024,1024] bf16 (reused)
  float* sums  = (float*)(ws + (26u << 20));
  float* sumsq = sums + HDIM;
  float* scale = sums + 2 * HDIM;
  float* shift = sums + 3 * HDIM;

  k_segsum<<<N_CORES, 256, 0, stream>>>(x, corelen, Abf);

  const float* Ws[3]  = {W1, W2, W3};
  const float* bs[3]  = {b1, b2, b3};
  const float* gs[3]  = {g1, g2, g3};
  const float* bes[3] = {be1, be2, be3};
  for (int l = 0; l < 3; ++l) {
    k_transpose_bf16<<<dim3(32, 32), dim3(32, 8), 0, stream>>>(Ws[l], Wt);
    k_gemm_bt<<<dim3(N_CORES / 128, HDIM / 128), 256, 0, stream>>>(
        Abf, Wt, bs[l], Hpre, N_CORES, HDIM, HDIM);
    hipMemsetAsync(sums, 0, 2 * HDIM * sizeof(float), stream);
    k_colstats<<<dim3(HDIM / 256, 32), 256, 0, stream>>>(Hpre, sums, sumsq);
    k_finalize<<<HDIM / 256, 256, 0, stream>>>(sums, sumsq, gs[l], bes[l], scale, shift);
    k_norm_relu<<<(N_CORES * HDIM / 4) / 256, 256, 0, stream>>>(Hpre, scale, shift, Abf);
  }
  k_final<<<N_CORES / 4, 256, 0, stream>>>(Abf, W4, b4, out);
}

// Round 2
// 300.714 us; speedup vs baseline: 1.1301x; 1.1301x over previous
//
#include <hip/hip_runtime.h>
#include <hip/hip_bf16.h>
#include <stdint.h>

#define N_ROWS 262144
#define FEAT 1024
#define N_CORES 4096
#define HDIM 1024
#define BN_EPS 1e-5f

typedef __attribute__((ext_vector_type(8))) short bf16x8;
typedef __attribute__((ext_vector_type(4))) float f32x4;

__device__ __forceinline__ unsigned short f2bf(float f) {
  __hip_bfloat16 h = __float2bfloat16(f);
  return __builtin_bit_cast(unsigned short, h);
}
__device__ __forceinline__ float bf2f(unsigned short u) {
  unsigned int x = ((unsigned int)u) << 16;
  return __builtin_bit_cast(float, x);
}

// async global->LDS, 16B per lane, dest = uniform base + lane*16
__device__ __forceinline__ void gll16(const unsigned short* g, unsigned short* l) {
  __builtin_amdgcn_global_load_lds(
      (const __attribute__((address_space(1))) void*)g,
      (__attribute__((address_space(3))) void*)l, 16, 0, 0);
}

// ---------------------------------------------------------------- seg-sum
__global__ __launch_bounds__(256)
void k_segsum(const float* __restrict__ x, const int* __restrict__ corelen,
              unsigned short* __restrict__ aggb) {
  const int seg = blockIdx.x;
  const int t = threadIdx.x;
  const int start = corelen[seg];
  const int end = (seg + 1 < N_CORES) ? corelen[seg + 1] : N_ROWS;
  float4 a0 = make_float4(0.f, 0.f, 0.f, 0.f);
  float4 a1 = make_float4(0.f, 0.f, 0.f, 0.f);
  const float* xp = x + (size_t)start * FEAT + t * 4;
  int r = start;
  for (; r + 2 <= end; r += 2) {
    const float4 v0 = *(const float4*)xp;
    const float4 v1 = *(const float4*)(xp + FEAT);
    a0.x += v0.x; a0.y += v0.y; a0.z += v0.z; a0.w += v0.w;
    a1.x += v1.x; a1.y += v1.y; a1.z += v1.z; a1.w += v1.w;
    xp += 2 * FEAT;
  }
  if (r < end) {
    const float4 v0 = *(const float4*)xp;
    a0.x += v0.x; a0.y += v0.y; a0.z += v0.z; a0.w += v0.w;
  }
  a0.x += a1.x; a0.y += a1.y; a0.z += a1.z; a0.w += a1.w;
  ushort4 o;
  o.x = f2bf(a0.x); o.y = f2bf(a0.y); o.z = f2bf(a0.z); o.w = f2bf(a0.w);
  *(ushort4*)(aggb + (size_t)seg * FEAT + t * 4) = o;
}

// ------------------------------------------- W [K,N] f32 -> Wt [N,K] bf16
__global__ __launch_bounds__(256)
void k_transpose_bf16(const float* __restrict__ W, unsigned short* __restrict__ Wt) {
  __shared__ unsigned short tile[32][33];
  const int tx = threadIdx.x, ty = threadIdx.y;
  const int n0 = blockIdx.x * 32, k0 = blockIdx.y * 32;
#pragma unroll
  for (int i = 0; i < 4; ++i)
    tile[ty + 8 * i][tx] = f2bf(W[(size_t)(k0 + ty + 8 * i) * HDIM + n0 + tx]);
  __syncthreads();
#pragma unroll
  for (int i = 0; i < 4; ++i)
    Wt[(size_t)(n0 + ty + 8 * i) * HDIM + k0 + tx] = tile[tx][ty + 8 * i];
}

// ------------------------------------------------------------------ GEMM
// C[M,N] = A[M,K](bf16) * Bt[N,K](bf16)^T + bias, fused BN column stats.
// BM=128, BN=64, BK=64; 4 waves, wave tile 64x32 (4x2 frags 16x16x32).
// LDS staged via global_load_lds (linear dest) with XOR-swizzled source
// columns; ds_read uses the matching swizzle -> 2-way bank alias (free).
#define BM 128
#define BN 64
#define BK 64
__global__ __launch_bounds__(256)
void k_gemm_bt(const unsigned short* __restrict__ A,
               const unsigned short* __restrict__ Bt,
               const float* __restrict__ bias,
               float* __restrict__ C,
               float* __restrict__ sums, float* __restrict__ sumsq) {
  __shared__ unsigned short As[BM * BK];
  __shared__ unsigned short Bs[BN * BK];
  const int t = threadIdx.x;
  const int lane = t & 63;
  const int w = t >> 6;
  const int tileM = blockIdx.x * BM;
  const int tileN = blockIdx.y * BN;
  const int wr = (w >> 1) * 64;   // wave row origin in tile
  const int wc = (w & 1) * 32;    // wave col origin in tile
  const int fr = lane & 15;
  const int kk = (lane >> 4) * 8;
  const int lr = lane >> 3;                       // staging sub-row 0..7
  const int sc = ((lane & 7) * 8) ^ (lr << 3);    // swizzled source k-col

  const unsigned short* pA = A + (size_t)(tileM + w * 32 + lr) * HDIM + sc;
  const unsigned short* pB = Bt + (size_t)(tileN + w * 16 + lr) * HDIM + sc;

  f32x4 acc[4][2] = {};

  for (int k0 = 0; k0 < HDIM; k0 += BK) {
#pragma unroll
    for (int j = 0; j < 4; ++j)
      gll16(pA + k0 + j * 8 * HDIM, As + (w * 32 + j * 8) * BK);
#pragma unroll
    for (int j = 0; j < 2; ++j)
      gll16(pB + k0 + j * 8 * HDIM, Bs + (w * 16 + j * 8) * BK);
    __syncthreads();   // drains vmcnt -> staged data visible
#pragma unroll
    for (int ks = 0; ks < 2; ++ks) {
      const int pc = (ks * 32 + kk) ^ ((fr & 7) << 3);  // swizzled read col
      bf16x8 af[4], bf[2];
#pragma unroll
      for (int m = 0; m < 4; ++m)
        af[m] = *(const bf16x8*)&As[(wr + m * 16 + fr) * BK + pc];
#pragma unroll
      for (int n = 0; n < 2; ++n)
        bf[n] = *(const bf16x8*)&Bs[(wc + n * 16 + fr) * BK + pc];
#pragma unroll
      for (int m = 0; m < 4; ++m)
#pragma unroll
        for (int n = 0; n < 2; ++n)
          acc[m][n] = __builtin_amdgcn_mfma_f32_16x16x32_bf16(af[m], bf[n], acc[m][n], 0, 0, 0);
    }
    __syncthreads();   // all reads done before next-tile overwrite
  }

  // epilogue: bias, store f32 H, fused per-column partial BN stats
  const int cr = (lane >> 4) * 4;
  const int cc = lane & 15;
#pragma unroll
  for (int n = 0; n < 2; ++n) {
    const int col = tileN + wc + n * 16 + cc;
    const float bv = bias[col];
    float s = 0.f, s2 = 0.f;
#pragma unroll
    for (int m = 0; m < 4; ++m) {
      float* cp = C + (size_t)(tileM + wr + m * 16 + cr) * HDIM + col;
#pragma unroll
      for (int j = 0; j < 4; ++j) {
        const float h = acc[m][n][j] + bv;
        cp[(size_t)j * HDIM] = h;
        s += h; s2 += h * h;
      }
    }
    s  += __shfl_xor(s, 16, 64);  s  += __shfl_xor(s, 32, 64);
    s2 += __shfl_xor(s2, 16, 64); s2 += __shfl_xor(s2, 32, 64);
    if ((lane >> 4) == 0) {
      atomicAdd(&sums[col], s);
      atomicAdd(&sumsq[col], s2);
    }
  }
}

__global__ __launch_bounds__(256)
void k_finalize(const float* __restrict__ sums, const float* __restrict__ sumsq,
                const float* __restrict__ g, const float* __restrict__ be,
                float* __restrict__ scale, float* __restrict__ shift) {
  const int c = blockIdx.x * 256 + threadIdx.x;
  const float mean = sums[c] * (1.f / N_CORES);
  const float var = sumsq[c] * (1.f / N_CORES) - mean * mean;
  const float sc = g[c] * rsqrtf(var + BN_EPS);
  scale[c] = sc;
  shift[c] = be[c] - mean * sc;
}

// ---------------------------------------- normalize + ReLU + cast to bf16
__global__ __launch_bounds__(256)
void k_norm_relu(const float* __restrict__ Hp, const float* __restrict__ scale,
                 const float* __restrict__ shift, unsigned short* __restrict__ Ab) {
  const size_t i4 = ((size_t)blockIdx.x * 256 + threadIdx.x) * 4;
  const float4 v = *(const float4*)(Hp + i4);
  const int c = (int)(i4 & (HDIM - 1));
  const float4 sc = *(const float4*)(scale + c);
  const float4 sh = *(const float4*)(shift + c);
  ushort4 o;
  o.x = f2bf(fmaxf(v.x * sc.x + sh.x, 0.f));
  o.y = f2bf(fmaxf(v.y * sc.y + sh.y, 0.f));
  o.z = f2bf(fmaxf(v.z * sc.z + sh.z, 0.f));
  o.w = f2bf(fmaxf(v.w * sc.w + sh.w, 0.f));
  *(ushort4*)(Ab + i4) = o;
}

// ----------------------------------------------- final layer [4096,1024]x[1024,2]
__global__ __launch_bounds__(256)
void k_final(const unsigned short* __restrict__ Ab, const float* __restrict__ W4,
             const float* __restrict__ b4, float* __restrict__ out) {
  const int t = threadIdx.x;
  const int w = t >> 6, lane = t & 63;
  const int row = blockIdx.x * 4 + w;
  const unsigned short* a = Ab + (size_t)row * HDIM + lane * 16;
  const bf16x8 v0 = *(const bf16x8*)a;
  const bf16x8 v1 = *(const bf16x8*)(a + 8);
  float s0 = 0.f, s1 = 0.f;
  const int kbase = lane * 16;
#pragma unroll
  for (int j = 0; j < 8; ++j) {
    const float av = bf2f((unsigned short)v0[j]);
    s0 += av * W4[(kbase + j) * 2 + 0];
    s1 += av * W4[(kbase + j) * 2 + 1];
  }
#pragma unroll
  for (int j = 0; j < 8; ++j) {
    const float av = bf2f((unsigned short)v1[j]);
    s0 += av * W4[(kbase + 8 + j) * 2 + 0];
    s1 += av * W4[(kbase + 8 + j) * 2 + 1];
  }
#pragma unroll
  for (int off = 32; off >= 1; off >>= 1) {
    s0 += __shfl_down(s0, off, 64);
    s1 += __shfl_down(s1, off, 64);
  }
  if (lane == 0) {
    out[row * 2 + 0] = s0 + b4[0];
    out[row * 2 + 1] = s1 + b4[1];
  }
}

extern "C" void kernel_launch(void* const* d_in, const int* in_sizes, int n_in,
                              void* d_out, int out_size, void* d_ws, size_t ws_size,
                              hipStream_t stream) {
  (void)in_sizes; (void)n_in; (void)out_size; (void)ws_size;
  const float* x       = (const float*)d_in[0];
  const int* corelen   = (const int*)d_in[1];
  const float* W1  = (const float*)d_in[2];
  const float* b1  = (const float*)d_in[3];
  const float* g1  = (const float*)d_in[4];
  const float* be1 = (const float*)d_in[5];
  const float* W2  = (const float*)d_in[6];
  const float* b2  = (const float*)d_in[7];
  const float* g2  = (const float*)d_in[8];
  const float* be2 = (const float*)d_in[9];
  const float* W3  = (const float*)d_in[10];
  const float* b3  = (const float*)d_in[11];
  const float* g3  = (const float*)d_in[12];
  const float* be3 = (const float*)d_in[13];
  const float* W4  = (const float*)d_in[14];
  const float* b4  = (const float*)d_in[15];
  float* out = (float*)d_out;

  char* ws = (char*)d_ws;
  float* Hpre          = (float*)(ws);                        // 16 MB [4096,1024] f32
  unsigned short* Abf  = (unsigned short*)(ws + (16u << 20)); //  8 MB [4096,1024] bf16
  unsigned short* Wt   = (unsigned short*)(ws + (24u << 20)); //  2 MB [1024,1024] bf16
  float* stats = (float*)(ws + (26u << 20));                  // 6*1024 f32 (per-layer sums/sumsq)
  float* scale = stats + 6 * HDIM;
  float* shift = scale + HDIM;

  hipMemsetAsync(stats, 0, 6 * HDIM * sizeof(float), stream);
  k_segsum<<<N_CORES, 256, 0, stream>>>(x, corelen, Abf);

  const float* Ws[3]  = {W1, W2, W3};
  const float* bs[3]  = {b1, b2, b3};
  const float* gs[3]  = {g1, g2, g3};
  const float* bes[3] = {be1, be2, be3};
  for (int l = 0; l < 3; ++l) {
    float* sums  = stats + l * 2 * HDIM;
    float* sumsq = sums + HDIM;
    k_transpose_bf16<<<dim3(32, 32), dim3(32, 8), 0, stream>>>(Ws[l], Wt);
    k_gemm_bt<<<dim3(N_CORES / BM, HDIM / BN), 256, 0, stream>>>(
        Abf, Wt, bs[l], Hpre, sums, sumsq);
    k_finalize<<<HDIM / 256, 256, 0, stream>>>(sums, sumsq, gs[l], bes[l], scale, shift);
    k_norm_relu<<<(N_CORES * HDIM / 4) / 256, 256, 0, stream>>>(Hpre, scale, shift, Abf);
  }
  k_final<<<N_CORES / 4, 256, 0, stream>>>(Abf, W4, b4, out);
}